// Round 14
// baseline (147.128 us; speedup 1.0000x reference)
//
#include <hip/hip_runtime.h>

// LSTM: B=8192 seqs, T=512, D=5, H=10, Linear(10,1) head.
// R14: software-SMT. Wave = 8 seqs as TWO independent 4-seq groups;
// 1024 waves = 1 wave/SIMD. Per timestep the wave issues group A's step
// and group B's step back-to-back: the two dependency chains are fully
// independent, so B's issue fills A's serial-tail stalls (and vice versa)
// -- guaranteed latency hiding instead of relying on 2-wave hardware SMT
// (which measured only 75% slot fill). Weights (Af) shared across groups.
// Per group: 4 chained/paired masked-B mfma_f32_16x16x16_f16 (R13),
// quad_perm DPP h-exchange (u=4g+q-6), exp2-domain pre-scaled f16 weights,
// R6 fused single-rcp activation tail. x double-buffered in registers,
// BSTEP=4 (smaller bufs: 80 VGPR for 2 groups; prefetch distance ~2400
// issue-cyc >> HBM latency). LDS only for the final head reduction.

#define BATCH  8192
#define SEQLEN 512
#define INSZ   5
#define HID    10
#define BSTEP  4                 // steps per x block
#define BV     5                 // f32x4 regs per block (BSTEP*INSZ/4)

#define L2E  1.442695040888963f   // log2(e)
#define L2E2 2.885390081777927f   // 2*log2(e)

typedef float     f32x4 __attribute__((ext_vector_type(4)));
typedef _Float16  f16x4 __attribute__((ext_vector_type(4)));
typedef unsigned  u32x2 __attribute__((ext_vector_type(2)));

__device__ __forceinline__ unsigned pkh(float a, float b) {
    return __builtin_bit_cast(unsigned, __builtin_amdgcn_cvt_pkrtz(a, b));
}
__device__ __forceinline__ f16x4 mkab(unsigned lo, unsigned hi) {
    u32x2 t; t.x = lo; t.y = hi;
    return __builtin_bit_cast(f16x4, t);
}
__device__ __forceinline__ f32x4 mfma16(f16x4 a, f16x4 b, f32x4 c) {
    return __builtin_amdgcn_mfma_f32_16x16x16f16(a, b, c, 0, 0, 0);
}
// Broadcast quad lane Q (0..3) to all 4 lanes of each quad (quad_perm DPP).
template<int Q>
__device__ __forceinline__ float quadbcast(float v) {
    int r = __builtin_amdgcn_update_dpp(0, __builtin_bit_cast(int, v),
                                        Q * 0x55, 0xF, 0xF, false);
    return __builtin_bit_cast(float, r);
}

__global__ __launch_bounds__(256, 1) void lstm_mfma(
    const float* __restrict__ x,     // [B, T, D]
    const float* __restrict__ Wih,   // [4H, D]
    const float* __restrict__ Whh,   // [4H, H]
    const float* __restrict__ bih,   // [4H]
    const float* __restrict__ bhh,   // [4H]
    const float* __restrict__ Wout,  // [1, H]
    const float* __restrict__ bout,  // [1]
    float* __restrict__ out)         // [B, 1]
{
    const int lane  = threadIdx.x & 63;
    const int wid   = threadIdx.x >> 6;
    const int gwave = (blockIdx.x * blockDim.x + threadIdx.x) >> 6;   // 0..1023
    const int col   = lane & 15;     // output tile column = 4*sq + q
    const int g     = lane >> 4;     // k/row group
    const int q     = col & 3;       // quad position = chunk selector
    const int sq    = col >> 2;      // seq-within-group (0..3)
    const size_t seqA = (size_t)gwave * 4 + sq;          // group A
    const size_t seqB = seqA + 4096;                     // group B

    __shared__ unsigned short hsh[4][96];   // final-h exchange (48 per group)

    // Unit computed by this lane: u = 4g+q-6 (slot-aligned; <0 => pad).
    const int u = 4 * g + q - 6;
    const bool uvalid = (u >= 0) && (u < HID);

    // ---- A fragments (4 chunks), shared by both groups ----
    // Chunk p, row r (= lane's col): unit 4*(r>>2)+p-6, gate r&3.
    // k-slot j: j<5 -> Wih[:,j]; j==5 -> bias; j>=6 -> Whh[:,j-6].
    // Pre-scale: gate 2 (g-gate) by +2log2e, others by -log2e (exp2 domain).
    f16x4 Af[4];
#pragma unroll
    for (int p = 0; p < 4; ++p) {
        const int ug   = 4 * (col >> 2) + p - 6;
        const int gate = col & 3;
        const bool v   = (ug >= 0) && (ug < HID);
        const int uc   = v ? ug : 0;
        const int orow = gate * HID + uc;
        const float sg = (gate == 2) ? L2E2 : -L2E;
        f16x4 a;
#pragma unroll
        for (int e = 0; e < 4; ++e) {
            const int jj = 4 * g + e;           // k slot
            float w;
            if (jj < 5)       w = Wih[orow * INSZ + jj];
            else if (jj == 5) w = bih[orow] + bhh[orow];
            else              w = Whh[orow * HID + (jj - 6)];
            a[e] = (_Float16)(v ? sg * w : 0.0f);
        }
        Af[p] = a;
    }

    const bool isG0 = (g == 0), isG1 = (g == 1);
    const bool isQ0 = (q == 0), isQ1 = (q == 1), isQ2 = (q == 2), isQ3 = (q == 3);

    const float* xpA = x + seqA * SEQLEN * INSZ;
    const float* xpB = x + seqB * SEQLEN * INSZ;
    float hA = 0.0f, csA = 0.0f;
    float hB = 0.0f, csB = 0.0f;

    f32x4 a0buf[BV], a1buf[BV], b0buf[BV], b1buf[BV];
    {
        const f32x4* vA = (const f32x4*)xpA;
        const f32x4* vB = (const f32x4*)xpB;
#pragma unroll
        for (int i = 0; i < BV; ++i) { a0buf[i] = vA[i]; b0buf[i] = vB[i]; }
    }

#define DO_STEP_G(cx, ss, h, cs)                                             \
    {                                                                        \
        const int ixb = (ss) * INSZ;                                         \
        const float xv0 = cx[(ixb + 0) >> 2][(ixb + 0) & 3];                 \
        const float xv1 = cx[(ixb + 1) >> 2][(ixb + 1) & 3];                 \
        const float xv2 = cx[(ixb + 2) >> 2][(ixb + 2) & 3];                 \
        const float xv3 = cx[(ixb + 3) >> 2][(ixb + 3) & 3];                 \
        const float xv4 = cx[(ixb + 4) >> 2][(ixb + 4) & 3];                 \
        const float b0 = quadbcast<0>(h), b1 = quadbcast<1>(h);              \
        const float b2 = quadbcast<2>(h), b3 = quadbcast<3>(h);              \
        const unsigned hAp = pkh(b0, b1), hBp = pkh(b2, b3);                 \
        const unsigned pairA = isG0 ? pkh(xv0, xv1)                          \
                             : (isG1 ? pkh(xv4, 1.0f) : hAp);                \
        const unsigned pairB = isG0 ? pkh(xv2, xv3) : hBp;                   \
        const f16x4 B0 = mkab(isQ0 ? pairA : 0u, isQ0 ? pairB : 0u);         \
        const f16x4 B1 = mkab(isQ1 ? pairA : 0u, isQ1 ? pairB : 0u);         \
        const f16x4 B2 = mkab(isQ2 ? pairA : 0u, isQ2 ? pairB : 0u);         \
        const f16x4 B3 = mkab(isQ3 ? pairA : 0u, isQ3 ? pairB : 0u);         \
        const f32x4 zz = {0.f, 0.f, 0.f, 0.f};                               \
        f32x4 t01 = mfma16(Af[0], B0, zz);                                   \
        t01 = mfma16(Af[1], B1, t01);                                        \
        f32x4 t23 = mfma16(Af[2], B2, zz);                                   \
        t23 = mfma16(Af[3], B3, t23);                                        \
        const f32x4 acc = t01 + t23;                                         \
        const float A_  = __builtin_amdgcn_exp2f(acc[0]);                    \
        const float E1_ = __builtin_amdgcn_exp2f(acc[1]);                    \
        const float U_  = __builtin_amdgcn_exp2f(acc[2]);                    \
        const float Bo_ = __builtin_amdgcn_exp2f(acc[3]);                    \
        const float t1 = 1.0f + A_;                                          \
        const float t2 = 1.0f + E1_;                                         \
        const float t3 = 1.0f + U_;                                          \
        const float um = fmaf(L2E2, U_, -L2E2);  /* 2log2e*(U-1) */          \
        const float m1 = t1 * t3;                                            \
        const float d1 = t2 * m1;                                            \
        const float r1v = __builtin_amdgcn_rcpf(d1);                         \
        const float num = fmaf(cs, m1, um * t2);                             \
        cs = num * r1v;                                                      \
        const float V = __builtin_amdgcn_exp2f(cs);                          \
        const float t4 = 1.0f + Bo_;                                         \
        const float t5 = 1.0f + V;                                           \
        const float r2v = __builtin_amdgcn_rcpf(t4 * t5);                    \
        h = (V - 1.0f) * r2v;                                                \
    }

    // 64 iterations x 2 phases of 4 steps; x buffer role swap (no copies).
    for (int it = 0; it < SEQLEN / (2 * BSTEP); ++it) {
        const int tb = it * 2 * BSTEP;
        {   // phase 0: prefetch next block into *1buf, compute from *0buf
            const f32x4* vA = (const f32x4*)(xpA + (tb + BSTEP) * INSZ);
            const f32x4* vB = (const f32x4*)(xpB + (tb + BSTEP) * INSZ);
#pragma unroll
            for (int i = 0; i < BV; ++i) { a1buf[i] = vA[i]; b1buf[i] = vB[i]; }
#pragma unroll
            for (int ss = 0; ss < BSTEP; ++ss) {
                DO_STEP_G(a0buf, ss, hA, csA)
                DO_STEP_G(b0buf, ss, hB, csB)
            }
        }
        {   // phase 1: prefetch block tb+2 into *0buf (clamped), compute *1buf
            int nb = tb + 2 * BSTEP;
            if (nb > SEQLEN - BSTEP) nb = SEQLEN - BSTEP;   // harmless reload
            const f32x4* vA = (const f32x4*)(xpA + nb * INSZ);
            const f32x4* vB = (const f32x4*)(xpB + nb * INSZ);
#pragma unroll
            for (int i = 0; i < BV; ++i) { a0buf[i] = vA[i]; b0buf[i] = vB[i]; }
#pragma unroll
            for (int ss = 0; ss < BSTEP; ++ss) {
                DO_STEP_G(a1buf, ss, hA, csA)
                DO_STEP_G(b1buf, ss, hB, csB)
            }
        }
    }
#undef DO_STEP_G

    // head: out[seq] = sum_u Wout[u]*h_u + bout (disjoint LDS region/group)
    const int baseA = sq * 10;
    const int baseB = 48 + sq * 10;
    const int wA = uvalid ? (baseA + u) : (40 + (lane & 7));
    const int wB = uvalid ? (baseB + u) : (88 + (lane & 7));
    hsh[wid][wA] = __builtin_bit_cast(unsigned short, (_Float16)hA);
    hsh[wid][wB] = __builtin_bit_cast(unsigned short, (_Float16)hB);
    asm volatile("s_waitcnt lgkmcnt(0)" ::: "memory");
    if (g == 0 && q == 0) {      // lanes 0,4,8,12 -> sq=0..3
        float rA = bout[0], rB = bout[0];
#pragma unroll
        for (int uu = 0; uu < HID; ++uu) {
            const float wv = Wout[uu];
            rA = fmaf(wv, (float)__builtin_bit_cast(_Float16, hsh[wid][baseA + uu]), rA);
            rB = fmaf(wv, (float)__builtin_bit_cast(_Float16, hsh[wid][baseB + uu]), rB);
        }
        out[seqA] = rA;
        out[seqB] = rB;
    }
}

extern "C" void kernel_launch(void* const* d_in, const int* in_sizes, int n_in,
                              void* d_out, int out_size, void* d_ws, size_t ws_size,
                              hipStream_t stream) {
    const float* x    = (const float*)d_in[0];
    const float* Wih  = (const float*)d_in[1];
    const float* Whh  = (const float*)d_in[2];
    const float* bih  = (const float*)d_in[3];
    const float* bhh  = (const float*)d_in[4];
    const float* Wout = (const float*)d_in[5];
    const float* bout = (const float*)d_in[6];
    float* out = (float*)d_out;

    const int threads = 256;
    const int blocks  = (BATCH / 8) * 64 / threads;  // 1024 waves = 256 blocks
    lstm_mfma<<<blocks, threads, 0, stream>>>(x, Wih, Whh, bih, bhh, Wout, bout, out);
}

// Round 15
// 113.980 us; speedup vs baseline: 1.2908x; 1.2908x over previous
//
#include <hip/hip_runtime.h>

// LSTM: B=8192 seqs, T=512, D=5, H=10, Linear(10,1) head.
// R15 (= R13 + serial-chain MFMA with bias-C + fma tail shave).
// Wave = 4 seqs, 2048 waves = 2/SIMD (R14 proved 1-wave software-SMT loses
// to 2-wave hardware SMT). The 4 chunk-MFMAs have disjoint masked columns,
// so a single serial chain seeded with the pre-scaled bias as C-operand is
// exact: acc = mfma(A3,B3,mfma(A2,B2,mfma(A1,B1,mfma(A0,B0,biasC)))) —
// kills the 4 acc-sum v_adds; bias leaves k-slot 5 (now zero).
// Quad_perm DPP h-exchange (u = 4g+q-6 slot-aligned, proven minimal),
// exp2-domain pre-scaled f16 weights, R6 fused single-rcp activation tail
// with h = fma(V, r2v, -r2v). 8-step register x double-buffer. LDS only
// for the final head reduction.

#define BATCH  8192
#define SEQLEN 512
#define INSZ   5
#define HID    10
#define BSTEP  8                 // steps per x block
#define BV     10                // f32x4 regs per block (BSTEP*INSZ/4)

#define L2E  1.442695040888963f   // log2(e)
#define L2E2 2.885390081777927f   // 2*log2(e)

typedef float     f32x4 __attribute__((ext_vector_type(4)));
typedef _Float16  f16x4 __attribute__((ext_vector_type(4)));
typedef unsigned  u32x2 __attribute__((ext_vector_type(2)));

__device__ __forceinline__ unsigned pkh(float a, float b) {
    return __builtin_bit_cast(unsigned, __builtin_amdgcn_cvt_pkrtz(a, b));
}
__device__ __forceinline__ f16x4 mkab(unsigned lo, unsigned hi) {
    u32x2 t; t.x = lo; t.y = hi;
    return __builtin_bit_cast(f16x4, t);
}
__device__ __forceinline__ f32x4 mfma16(f16x4 a, f16x4 b, f32x4 c) {
    return __builtin_amdgcn_mfma_f32_16x16x16f16(a, b, c, 0, 0, 0);
}
// Broadcast quad lane Q (0..3) to all 4 lanes of each quad (quad_perm DPP).
template<int Q>
__device__ __forceinline__ float quadbcast(float v) {
    int r = __builtin_amdgcn_update_dpp(0, __builtin_bit_cast(int, v),
                                        Q * 0x55, 0xF, 0xF, false);
    return __builtin_bit_cast(float, r);
}

__global__ __launch_bounds__(256, 2) void lstm_mfma(
    const float* __restrict__ x,     // [B, T, D]
    const float* __restrict__ Wih,   // [4H, D]
    const float* __restrict__ Whh,   // [4H, H]
    const float* __restrict__ bih,   // [4H]
    const float* __restrict__ bhh,   // [4H]
    const float* __restrict__ Wout,  // [1, H]
    const float* __restrict__ bout,  // [1]
    float* __restrict__ out)         // [B, 1]
{
    const int lane  = threadIdx.x & 63;
    const int wid   = threadIdx.x >> 6;
    const int gwave = (blockIdx.x * blockDim.x + threadIdx.x) >> 6;
    const int col   = lane & 15;     // output tile column = 4*sq + q
    const int g     = lane >> 4;     // k/row group
    const int q     = col & 3;       // quad position = chunk selector
    const int sq    = col >> 2;      // seq within wave (0..3)
    const size_t seq = (size_t)gwave * 4 + sq;

    __shared__ unsigned short hsh[4][48];   // final-h exchange only

    // Unit computed by this lane: u = 4g+q-6 (slot-aligned; <0 => pad).
    const int u = 4 * g + q - 6;
    const bool uvalid = (u >= 0) && (u < HID);

    // ---- A fragments (4 chunks) ----
    // Chunk p, row r (= constructing lane's col): unit 4*(r>>2)+p-6, gate r&3.
    // k-slot j: j<5 -> Wih[:,j]; j==5 -> ZERO (bias moved to C); j>=6 -> Whh[:,j-6].
    // Pre-scale: gate 2 (g-gate) by +2log2e, others by -log2e (exp2 domain).
    f16x4 Af[4];
#pragma unroll
    for (int p = 0; p < 4; ++p) {
        const int ug   = 4 * (col >> 2) + p - 6;
        const int gate = col & 3;
        const bool v   = (ug >= 0) && (ug < HID);
        const int uc   = v ? ug : 0;
        const int orow = gate * HID + uc;
        const float sg = (gate == 2) ? L2E2 : -L2E;
        f16x4 a;
#pragma unroll
        for (int e = 0; e < 4; ++e) {
            const int jj = 4 * g + e;           // k slot
            float w;
            if (jj < 5)       w = Wih[orow * INSZ + jj];
            else if (jj == 5) w = 0.0f;         // bias now in C operand
            else              w = Whh[orow * HID + (jj - 6)];
            a[e] = (_Float16)(v ? sg * w : 0.0f);
        }
        Af[p] = a;
    }

    // ---- bias as MFMA C operand ----
    // D/C layout: lane (col,g) reg r = gate r of unit u (this lane's unit).
    f32x4 biasC;
    {
        const int uc = uvalid ? u : 0;
#pragma unroll
        for (int r = 0; r < 4; ++r) {
            const int orow = r * HID + uc;
            const float sg = (r == 2) ? L2E2 : -L2E;
            biasC[r] = uvalid ? sg * (bih[orow] + bhh[orow]) : 0.0f;
        }
    }

    const bool isG0 = (g == 0), isG1 = (g == 1);
    const bool isQ0 = (q == 0), isQ1 = (q == 1), isQ2 = (q == 2), isQ3 = (q == 3);

    const float* xp = x + seq * SEQLEN * INSZ;
    float h  = 0.0f;
    float cs = 0.0f;   // exp2-scaled cell state of unit u, seq sq

    f32x4 bufA[BV], bufB[BV];
    {
        const f32x4* v4 = (const f32x4*)xp;
#pragma unroll
        for (int i = 0; i < BV; ++i) bufA[i] = v4[i];
    }

#define DO_STEP(cx, ss)                                                      \
    {                                                                        \
        const int ixb = (ss) * INSZ;                                         \
        const float xv0 = cx[(ixb + 0) >> 2][(ixb + 0) & 3];                 \
        const float xv1 = cx[(ixb + 1) >> 2][(ixb + 1) & 3];                 \
        const float xv2 = cx[(ixb + 2) >> 2][(ixb + 2) & 3];                 \
        const float xv3 = cx[(ixb + 3) >> 2][(ixb + 3) & 3];                 \
        const float xv4 = cx[(ixb + 4) >> 2][(ixb + 4) & 3];                 \
        /* h values for my k-slots 4g+{0..3}: quad broadcasts (DPP) */       \
        const float b0 = quadbcast<0>(h), b1 = quadbcast<1>(h);              \
        const float b2 = quadbcast<2>(h), b3 = quadbcast<3>(h);              \
        const unsigned hA = pkh(b0, b1), hB = pkh(b2, b3);                   \
        const unsigned pairA = isG0 ? pkh(xv0, xv1)                          \
                             : (isG1 ? pkh(xv4, 0.0f) : hA);                 \
        const unsigned pairB = isG0 ? pkh(xv2, xv3) : hB;                    \
        const f16x4 B0 = mkab(isQ0 ? pairA : 0u, isQ0 ? pairB : 0u);         \
        const f16x4 B1 = mkab(isQ1 ? pairA : 0u, isQ1 ? pairB : 0u);         \
        const f16x4 B2 = mkab(isQ2 ? pairA : 0u, isQ2 ? pairB : 0u);         \
        const f16x4 B3 = mkab(isQ3 ? pairA : 0u, isQ3 ? pairB : 0u);         \
        f32x4 acc = mfma16(Af[0], B0, biasC);                                \
        acc = mfma16(Af[1], B1, acc);                                        \
        acc = mfma16(Af[2], B2, acc);                                        \
        acc = mfma16(Af[3], B3, acc);                                        \
        const float A_  = __builtin_amdgcn_exp2f(acc[0]);                    \
        const float E1_ = __builtin_amdgcn_exp2f(acc[1]);                    \
        const float U_  = __builtin_amdgcn_exp2f(acc[2]);                    \
        const float Bo_ = __builtin_amdgcn_exp2f(acc[3]);                    \
        const float t1 = 1.0f + A_;                                          \
        const float t2 = 1.0f + E1_;                                         \
        const float t3 = 1.0f + U_;                                          \
        const float um = fmaf(L2E2, U_, -L2E2);  /* 2log2e*(U-1) */          \
        const float m1 = t1 * t3;                                            \
        const float d1 = t2 * m1;                                            \
        const float r1v = __builtin_amdgcn_rcpf(d1);                         \
        const float num = fmaf(cs, m1, um * t2);                             \
        cs = num * r1v;                                                      \
        const float V = __builtin_amdgcn_exp2f(cs);                          \
        const float t4 = 1.0f + Bo_;                                         \
        const float t5 = 1.0f + V;                                           \
        const float r2v = __builtin_amdgcn_rcpf(t4 * t5);                    \
        h = fmaf(V, r2v, -r2v);          /* (V-1)*r2v */                     \
    }

    // 32 iterations x 2 phases of 8 steps; x buffer role swap (no copies).
    for (int it = 0; it < SEQLEN / (2 * BSTEP); ++it) {
        const int tb = it * 2 * BSTEP;
        {
            const f32x4* v4 = (const f32x4*)(xp + (tb + BSTEP) * INSZ);
#pragma unroll
            for (int i = 0; i < BV; ++i) bufB[i] = v4[i];
#pragma unroll
            for (int ss = 0; ss < BSTEP; ++ss) DO_STEP(bufA, ss)
        }
        {
            int nb = tb + 2 * BSTEP;
            if (nb > SEQLEN - BSTEP) nb = SEQLEN - BSTEP;   // harmless reload
            const f32x4* v4 = (const f32x4*)(xp + nb * INSZ);
#pragma unroll
            for (int i = 0; i < BV; ++i) bufA[i] = v4[i];
#pragma unroll
            for (int ss = 0; ss < BSTEP; ++ss) DO_STEP(bufB, ss)
        }
    }
#undef DO_STEP

    // head: out[seq] = sum_u Wout[u]*h_u + bout (one LDS exchange, per wave)
    const int base = sq * 10;
    const int widx = uvalid ? (base + u) : (40 + (lane & 7));
    hsh[wid][widx] = __builtin_bit_cast(unsigned short, (_Float16)h);
    asm volatile("s_waitcnt lgkmcnt(0)" ::: "memory");
    if (g == 0 && q == 0) {      // lanes 0,4,8,12 -> seqs sq=0..3
        float r = bout[0];
#pragma unroll
        for (int uu = 0; uu < HID; ++uu) {
            const float hv = (float)__builtin_bit_cast(_Float16, hsh[wid][base + uu]);
            r = fmaf(Wout[uu], hv, r);
        }
        out[gwave * 4 + sq] = r;
    }
}

extern "C" void kernel_launch(void* const* d_in, const int* in_sizes, int n_in,
                              void* d_out, int out_size, void* d_ws, size_t ws_size,
                              hipStream_t stream) {
    const float* x    = (const float*)d_in[0];
    const float* Wih  = (const float*)d_in[1];
    const float* Whh  = (const float*)d_in[2];
    const float* bih  = (const float*)d_in[3];
    const float* bhh  = (const float*)d_in[4];
    const float* Wout = (const float*)d_in[5];
    const float* bout = (const float*)d_in[6];
    float* out = (float*)d_out;

    const int threads = 256;
    const int blocks  = (BATCH * 16) / threads;  // 512 blocks = 2048 waves
    lstm_mfma<<<blocks, threads, 0, stream>>>(x, Wih, Whh, bih, bhh, Wout, bout, out);
}

// Round 16
// 113.242 us; speedup vs baseline: 1.2992x; 1.0065x over previous
//
#include <hip/hip_runtime.h>

// LSTM: B=8192 seqs, T=512, D=5, H=10, Linear(10,1) head.
// R16 (= R15 + phase-level x pre-pack + setprio around MFMA chain).
// Wave = 4 seqs, 2048 waves = 2/SIMD. Per phase (8 steps): the x block
// (loaded one phase ahead into f32 staging) is converted ONCE to 24 packed
// f16 pairs (independent cvt burst, no wait), so DO_STEP's serial region
// loses its 3 cvt_pkrtz. Single staging + single pk buffer (WAR-safe:
// cvts read staging before the next loads are issued into it).
// s_setprio(1) brackets the serial MFMA chain: the two co-resident waves
// are independent free-runners (attn-like case where setprio helps).
// Everything else = R15: serial bias-C MFMA chain over 4 masked-B chunks,
// quad_perm DPP h-exchange (u=4g+q-6), exp2-domain pre-scaled f16 weights,
// fused single-rcp activation tail. LDS only for the final head reduction.

#define BATCH  8192
#define SEQLEN 512
#define INSZ   5
#define HID    10
#define BSTEP  8                 // steps per x block
#define BV     10                // f32x4 staging regs (BSTEP*INSZ/4)

#define L2E  1.442695040888963f   // log2(e)
#define L2E2 2.885390081777927f   // 2*log2(e)

typedef float     f32x4 __attribute__((ext_vector_type(4)));
typedef _Float16  f16x4 __attribute__((ext_vector_type(4)));
typedef unsigned  u32x2 __attribute__((ext_vector_type(2)));

__device__ __forceinline__ unsigned pkh(float a, float b) {
    return __builtin_bit_cast(unsigned, __builtin_amdgcn_cvt_pkrtz(a, b));
}
__device__ __forceinline__ f16x4 mkab(unsigned lo, unsigned hi) {
    u32x2 t; t.x = lo; t.y = hi;
    return __builtin_bit_cast(f16x4, t);
}
__device__ __forceinline__ f32x4 mfma16(f16x4 a, f16x4 b, f32x4 c) {
    return __builtin_amdgcn_mfma_f32_16x16x16f16(a, b, c, 0, 0, 0);
}
// Broadcast quad lane Q (0..3) to all 4 lanes of each quad (quad_perm DPP).
template<int Q>
__device__ __forceinline__ float quadbcast(float v) {
    int r = __builtin_amdgcn_update_dpp(0, __builtin_bit_cast(int, v),
                                        Q * 0x55, 0xF, 0xF, false);
    return __builtin_bit_cast(float, r);
}

__global__ __launch_bounds__(256, 2) void lstm_mfma(
    const float* __restrict__ x,     // [B, T, D]
    const float* __restrict__ Wih,   // [4H, D]
    const float* __restrict__ Whh,   // [4H, H]
    const float* __restrict__ bih,   // [4H]
    const float* __restrict__ bhh,   // [4H]
    const float* __restrict__ Wout,  // [1, H]
    const float* __restrict__ bout,  // [1]
    float* __restrict__ out)         // [B, 1]
{
    const int lane  = threadIdx.x & 63;
    const int wid   = threadIdx.x >> 6;
    const int gwave = (blockIdx.x * blockDim.x + threadIdx.x) >> 6;
    const int col   = lane & 15;     // output tile column = 4*sq + q
    const int g     = lane >> 4;     // k/row group
    const int q     = col & 3;       // quad position = chunk selector
    const int sq    = col >> 2;      // seq within wave (0..3)
    const size_t seq = (size_t)gwave * 4 + sq;

    __shared__ unsigned short hsh[4][48];   // final-h exchange only

    // Unit computed by this lane: u = 4g+q-6 (slot-aligned; <0 => pad).
    const int u = 4 * g + q - 6;
    const bool uvalid = (u >= 0) && (u < HID);

    // ---- A fragments (4 chunks) ----
    // Chunk p, row r: unit 4*(r>>2)+p-6, gate r&3.
    // k-slot j: j<5 -> Wih[:,j]; j==5 -> ZERO (bias in C); j>=6 -> Whh[:,j-6].
    // Pre-scale: gate 2 (g-gate) by +2log2e, others by -log2e (exp2 domain).
    f16x4 Af[4];
#pragma unroll
    for (int p = 0; p < 4; ++p) {
        const int ug   = 4 * (col >> 2) + p - 6;
        const int gate = col & 3;
        const bool v   = (ug >= 0) && (ug < HID);
        const int uc   = v ? ug : 0;
        const int orow = gate * HID + uc;
        const float sg = (gate == 2) ? L2E2 : -L2E;
        f16x4 a;
#pragma unroll
        for (int e = 0; e < 4; ++e) {
            const int jj = 4 * g + e;           // k slot
            float w;
            if (jj < 5)       w = Wih[orow * INSZ + jj];
            else if (jj == 5) w = 0.0f;         // bias now in C operand
            else              w = Whh[orow * HID + (jj - 6)];
            a[e] = (_Float16)(v ? sg * w : 0.0f);
        }
        Af[p] = a;
    }

    // ---- bias as MFMA C operand (D reg r = gate r of this lane's unit) ----
    f32x4 biasC;
    {
        const int uc = uvalid ? u : 0;
#pragma unroll
        for (int r = 0; r < 4; ++r) {
            const int orow = r * HID + uc;
            const float sg = (r == 2) ? L2E2 : -L2E;
            biasC[r] = uvalid ? sg * (bih[orow] + bhh[orow]) : 0.0f;
        }
    }

    const bool isG0 = (g == 0), isG1 = (g == 1);
    const bool isQ0 = (q == 0), isQ1 = (q == 1), isQ2 = (q == 2), isQ3 = (q == 3);

    const float* xp = x + seq * SEQLEN * INSZ;
    float h  = 0.0f;
    float cs = 0.0f;   // exp2-scaled cell state of unit u, seq sq

    // f32 staging (one block) + packed-f16 pairs for the current block.
    f32x4 stage[BV];
    unsigned pk[3 * BSTEP];
    {
        const f32x4* v4 = (const f32x4*)xp;
#pragma unroll
        for (int i = 0; i < BV; ++i) stage[i] = v4[i];
    }

#define DO_STEP(ss)                                                          \
    {                                                                        \
        /* h values for my k-slots 4g+{0..3}: quad broadcasts (DPP) */       \
        const float b0 = quadbcast<0>(h), b1 = quadbcast<1>(h);              \
        const float b2 = quadbcast<2>(h), b3 = quadbcast<3>(h);              \
        const unsigned hA = pkh(b0, b1), hB = pkh(b2, b3);                   \
        const unsigned pairA = isG0 ? pk[3 * (ss) + 0]                       \
                             : (isG1 ? pk[3 * (ss) + 2] : hA);               \
        const unsigned pairB = isG0 ? pk[3 * (ss) + 1] : hB;                 \
        const f16x4 B0 = mkab(isQ0 ? pairA : 0u, isQ0 ? pairB : 0u);         \
        const f16x4 B1 = mkab(isQ1 ? pairA : 0u, isQ1 ? pairB : 0u);         \
        const f16x4 B2 = mkab(isQ2 ? pairA : 0u, isQ2 ? pairB : 0u);         \
        const f16x4 B3 = mkab(isQ3 ? pairA : 0u, isQ3 ? pairB : 0u);         \
        __builtin_amdgcn_s_setprio(1);                                       \
        f32x4 acc = mfma16(Af[0], B0, biasC);                                \
        acc = mfma16(Af[1], B1, acc);                                        \
        acc = mfma16(Af[2], B2, acc);                                        \
        acc = mfma16(Af[3], B3, acc);                                        \
        __builtin_amdgcn_s_setprio(0);                                       \
        const float A_  = __builtin_amdgcn_exp2f(acc[0]);                    \
        const float E1_ = __builtin_amdgcn_exp2f(acc[1]);                    \
        const float U_  = __builtin_amdgcn_exp2f(acc[2]);                    \
        const float Bo_ = __builtin_amdgcn_exp2f(acc[3]);                    \
        const float t1 = 1.0f + A_;                                          \
        const float t2 = 1.0f + E1_;                                         \
        const float t3 = 1.0f + U_;                                          \
        const float um = fmaf(L2E2, U_, -L2E2);  /* 2log2e*(U-1) */          \
        const float m1 = t1 * t3;                                            \
        const float d1 = t2 * m1;                                            \
        const float r1v = __builtin_amdgcn_rcpf(d1);                         \
        const float num = fmaf(cs, m1, um * t2);                             \
        cs = num * r1v;                                                      \
        const float V = __builtin_amdgcn_exp2f(cs);                          \
        const float t4 = 1.0f + Bo_;                                         \
        const float t5 = 1.0f + V;                                           \
        const float r2v = __builtin_amdgcn_rcpf(t4 * t5);                    \
        h = fmaf(V, r2v, -r2v);          /* (V-1)*r2v */                     \
    }

    // 64 phases of 8 steps. Per phase: convert staged block -> pk (burst,
    // data resident), then issue next block's loads into staging (WAR-safe),
    // then 8 steps. Prefetch distance = one full phase >> HBM latency.
    for (int it = 0; it < SEQLEN / BSTEP; ++it) {
        // convert the block loaded last phase (element s*5+k at static idx)
#pragma unroll
        for (int ss = 0; ss < BSTEP; ++ss) {
            const int ixb = ss * INSZ;
            const float xv0 = stage[(ixb + 0) >> 2][(ixb + 0) & 3];
            const float xv1 = stage[(ixb + 1) >> 2][(ixb + 1) & 3];
            const float xv2 = stage[(ixb + 2) >> 2][(ixb + 2) & 3];
            const float xv3 = stage[(ixb + 3) >> 2][(ixb + 3) & 3];
            const float xv4 = stage[(ixb + 4) >> 2][(ixb + 4) & 3];
            pk[3 * ss + 0] = pkh(xv0, xv1);
            pk[3 * ss + 1] = pkh(xv2, xv3);
            pk[3 * ss + 2] = pkh(xv4, 0.0f);
        }
        // issue next block's loads (clamped on last phase; harmless reload)
        {
            int nb = it + 1;
            if (nb > SEQLEN / BSTEP - 1) nb = SEQLEN / BSTEP - 1;
            const f32x4* v4 = (const f32x4*)(xp + nb * BSTEP * INSZ);
#pragma unroll
            for (int i = 0; i < BV; ++i) stage[i] = v4[i];
        }
#pragma unroll
        for (int ss = 0; ss < BSTEP; ++ss) DO_STEP(ss)
    }
#undef DO_STEP

    // head: out[seq] = sum_u Wout[u]*h_u + bout (one LDS exchange, per wave)
    const int base = sq * 10;
    const int widx = uvalid ? (base + u) : (40 + (lane & 7));
    hsh[wid][widx] = __builtin_bit_cast(unsigned short, (_Float16)h);
    asm volatile("s_waitcnt lgkmcnt(0)" ::: "memory");
    if (g == 0 && q == 0) {      // lanes 0,4,8,12 -> seqs sq=0..3
        float r = bout[0];
#pragma unroll
        for (int uu = 0; uu < HID; ++uu) {
            const float hv = (float)__builtin_bit_cast(_Float16, hsh[wid][base + uu]);
            r = fmaf(Wout[uu], hv, r);
        }
        out[gwave * 4 + sq] = r;
    }
}

extern "C" void kernel_launch(void* const* d_in, const int* in_sizes, int n_in,
                              void* d_out, int out_size, void* d_ws, size_t ws_size,
                              hipStream_t stream) {
    const float* x    = (const float*)d_in[0];
    const float* Wih  = (const float*)d_in[1];
    const float* Whh  = (const float*)d_in[2];
    const float* bih  = (const float*)d_in[3];
    const float* bhh  = (const float*)d_in[4];
    const float* Wout = (const float*)d_in[5];
    const float* bout = (const float*)d_in[6];
    float* out = (float*)d_out;

    const int threads = 256;
    const int blocks  = (BATCH * 16) / threads;  // 512 blocks = 2048 waves
    lstm_mfma<<<blocks, threads, 0, stream>>>(x, Wih, Whh, bih, bhh, Wout, bout, out);
}